// Round 9
// baseline (1475.047 us; speedup 1.0000x reference)
//
#include <hip/hip_runtime.h>

#define NPTS   4096
#define NB     8
#define M1     1024     // ceil(0.25*4096)
#define M2     820      // ceil(0.2*4096)
#define MQ     9830     // 8*1024 + 1638
#define KK     16

typedef unsigned int u32;
typedef unsigned long long u64;
typedef float f32x2 __attribute__((ext_vector_type(2)));

// 2-wide DPP lexicographic combine on (khi_,klo_) u64 key. VALU pipe.
// 0x121/0x122/0x124/0x128 = row_ror 1/2/4/8; 0x142/0x143 = row_bcast15/31.
// Lane 63 ends with the wave max. Proven bit-exact R2-R8.
#define DPP_MAX(CTRL) do {                                                         \
    u32 olo_ = (u32)__builtin_amdgcn_update_dpp((int)klo_, (int)klo_, CTRL, 0xF, 0xF, false); \
    u32 ohi_ = (u32)__builtin_amdgcn_update_dpp((int)khi_, (int)khi_, CTRL, 0xF, 0xF, false); \
    u64 ok_ = ((u64)ohi_ << 32) | olo_;                                            \
    u64 ck_ = ((u64)khi_ << 32) | klo_;                                            \
    if (ok_ > ck_) { klo_ = olo_; khi_ = ohi_; }                                   \
} while (0)

#define DPP_MIN(CTRL) do {                                                         \
    u32 olo_ = (u32)__builtin_amdgcn_update_dpp((int)klo_, (int)klo_, CTRL, 0xF, 0xF, false); \
    u32 ohi_ = (u32)__builtin_amdgcn_update_dpp((int)khi_, (int)khi_, CTRL, 0xF, 0xF, false); \
    u64 ok_ = ((u64)ohi_ << 32) | olo_;                                            \
    u64 ck_ = ((u64)khi_ << 32) | klo_;                                            \
    if (ok_ < ck_) { klo_ = olo_; khi_ = ohi_; }                                   \
} while (0)

// ---------------- FPS: 4 waves (256 thr) per cloud, BARRIER-FREE ----------------
// Bit-exact vs jax: d = ((dx*dx+dy*dy)+dz*dz) f32 no-contract; min(MD,d);
// argmax tie -> lowest idx. Key = dist_bits(32) << 32 | (4095-idx)(12b) << 12 |
// stamp s (12b): stamp bits are equal across same-step candidates so they never
// affect the max; (4095-idx) gives tie -> lowest index.
// Exchange = stamped-slot dataflow: winner lane writes 4 self-stamped b64 words
// {x,s}{y,s}{z,s}{klo|s,khi}; all waves poll-read + validate ALL stamps (no
// write-order assumption; b64 is one DS op). Parity double-buffer: a wave can
// publish s+2 into slot[par(s)] only after every wave consumed step s (proof:
// publishing s+2 requires polling s+1 complete, which requires everyone
// published s+1, which requires everyone consumed s). No s_barrier in the loop.
__global__ __launch_bounds__(256) void fps_kernel(const float* __restrict__ pos,
                                                  int* __restrict__ picks) {
#pragma clang fp contract(off)
    __shared__ float sx[NPTS], sy[NPTS], sz[NPTS];
    __shared__ __align__(16) u32 slots[2][4][8];  // [par][wave][x,s, y,s, z,s, klo,khi]
    const int b = blockIdx.x;
    const int t = threadIdx.x;
    const float* cp = pos + (size_t)b * NPTS * 3;
    for (int i = t; i < NPTS * 3; i += 256) {
        float v = cp[i];
        int p = i / 3, c = i - p * 3;
        if (c == 0) sx[p] = v;
        else if (c == 1) sy[p] = v;
        else sz[p] = v;
    }
    if (t < 64) ((u32*)slots)[t] = 0xFFFFFFFFu;   // invalid stamps (LDS garbage defense)
    if (t == 0) picks[b * M1] = 0;
    __syncthreads();

    f32x2 X[8], Y[8], Z[8], MD[8];
#pragma unroll
    for (int r = 0; r < 8; ++r) {
        int p0 = (2 * r) * 256 + t, p1 = p0 + 256;
        X[r] = f32x2{sx[p0], sx[p1]};
        Y[r] = f32x2{sy[p0], sy[p1]};
        Z[r] = f32x2{sz[p0], sz[p1]};
        MD[r] = f32x2{__builtin_inff(), __builtin_inff()};
    }
    float xl = sx[0], yl = sy[0], zl = sz[0];
    const int wave = t >> 6;

    for (int s = 1; s < M1; ++s) {
        const int par = s & 1;
        const f32x2 xl2 = f32x2{xl, xl};
        const f32x2 yl2 = f32x2{yl, yl};
        const f32x2 zl2 = f32x2{zl, zl};
        float mv[8];
        int mi[8];
#pragma unroll
        for (int r = 0; r < 8; ++r) {
            f32x2 dx = X[r] - xl2;
            f32x2 dy = Y[r] - yl2;
            f32x2 dz = Z[r] - zl2;
            f32x2 d = (dx * dx + dy * dy) + dz * dz;        // contract(off)
            f32x2 m = __builtin_elementwise_min(MD[r], d);
            MD[r] = m;
            bool c = m[1] > m[0];            // slot 2r has lower point index
            mv[r] = c ? m[1] : m[0];
            mi[r] = c ? 2 * r + 1 : 2 * r;
        }
        // tree; left always lower index -> strict > keeps lowest on ties
#pragma unroll
        for (int st = 4; st >= 1; st >>= 1) {
#pragma unroll
            for (int i = 0; i < 8; ++i) {
                if (i < st) {
                    if (mv[i + st] > mv[i]) { mv[i] = mv[i + st]; mi[i] = mi[i + st]; }
                }
            }
        }
        const int ci = (mi[0] << 8) + t;
        // own-candidate xyz: issued here (2-way bank alias = free); the waitcnt
        // for them lands inside the winner branch, hidden under the DPP chain.
        float cx = sx[ci], cy = sy[ci], cz = sz[ci];
        __builtin_amdgcn_sched_barrier(0);    // keep loads above the DPP chain
        u32 klo_ = (((u32)(4095 - ci)) << 12) | (u32)s;
        u32 khi_ = __float_as_uint(mv[0]);
        const u32 mylo = klo_;
        DPP_MAX(0x121); DPP_MAX(0x122); DPP_MAX(0x124); DPP_MAX(0x128);
        DPP_MAX(0x142); DPP_MAX(0x143);
        const u32 wlo = (u32)__builtin_amdgcn_readlane((int)klo_, 63);
        if (mylo == wlo) {                    // unique winner lane per wave
            volatile u64* sl = (volatile u64*)&slots[par][wave][0];
            const u64 st64 = (u64)(u32)s << 32;
            sl[0] = st64 | __float_as_uint(cx);
            sl[1] = st64 | __float_as_uint(cy);
            sl[2] = st64 | __float_as_uint(cz);
            sl[3] = ((u64)khi_ << 32) | mylo; // key word is self-stamped (low 12 = s)
        }
        // dataflow wait: poll all 4 wave slots until every stamp == s
        u64 xw0, yw0, zw0, kw0, xw1, yw1, zw1, kw1;
        u64 xw2, yw2, zw2, kw2, xw3, yw3, zw3, kw3;
        for (;;) {
            volatile u64* s0 = (volatile u64*)&slots[par][0][0];
            volatile u64* s1 = (volatile u64*)&slots[par][1][0];
            volatile u64* s2 = (volatile u64*)&slots[par][2][0];
            volatile u64* s3 = (volatile u64*)&slots[par][3][0];
            xw0 = s0[0]; yw0 = s0[1]; zw0 = s0[2]; kw0 = s0[3];
            xw1 = s1[0]; yw1 = s1[1]; zw1 = s1[2]; kw1 = s1[3];
            xw2 = s2[0]; yw2 = s2[1]; zw2 = s2[2]; kw2 = s2[3];
            xw3 = s3[0]; yw3 = s3[1]; zw3 = s3[2]; kw3 = s3[3];
            const u32 us = (u32)s;
            bool ok = ((u32)(xw0 >> 32) == us) & ((u32)(yw0 >> 32) == us) &
                      ((u32)(zw0 >> 32) == us) & (((u32)kw0 & 0xFFFu) == us) &
                      ((u32)(xw1 >> 32) == us) & ((u32)(yw1 >> 32) == us) &
                      ((u32)(zw1 >> 32) == us) & (((u32)kw1 & 0xFFFu) == us) &
                      ((u32)(xw2 >> 32) == us) & ((u32)(yw2 >> 32) == us) &
                      ((u32)(zw2 >> 32) == us) & (((u32)kw2 & 0xFFFu) == us) &
                      ((u32)(xw3 >> 32) == us) & ((u32)(yw3 >> 32) == us) &
                      ((u32)(zw3 >> 32) == us) & (((u32)kw3 & 0xFFFu) == us);
            if (ok) break;                    // wave-uniform branch
        }
        // select max key, carrying payload
        u64 ka = kw0; u32 xa = (u32)xw0, ya = (u32)yw0, za = (u32)zw0;
        if (kw1 > ka) { ka = kw1; xa = (u32)xw1; ya = (u32)yw1; za = (u32)zw1; }
        u64 kb = kw2; u32 xb = (u32)xw2, yb = (u32)yw2, zb = (u32)zw2;
        if (kw3 > kb) { kb = kw3; xb = (u32)xw3; yb = (u32)yw3; zb = (u32)zw3; }
        if (kb > ka) { ka = kb; xa = xb; ya = yb; za = zb; }
        xl = __uint_as_float(xa); yl = __uint_as_float(ya); zl = __uint_as_float(za);
        if (t == 0) picks[b * M1 + s] = 4095 - (int)(((u32)ka) >> 12);  // never waited
    }
}

// ---------------- build combined_idx + row ----------------
__global__ __launch_bounds__(256) void build_kernel(const int* __restrict__ picks,
                                                    int* __restrict__ out) {
    int i = blockIdx.x * 256 + threadIdx.x;
    if (i < MQ) {
        int v;
        if (i < NB * M1) {
            int b = i >> 10;
            v = b * NPTS + picks[i];
        } else {
            int e = i - NB * M1;
            int b = e / M2;
            int j = e - b * M2;
            v = b * NPTS + picks[b * M1 + j];      // extra = prefix of base FPS
        }
        out[i] = v;
    }
    if (i < MQ * KK) {
        out[MQ + i] = i >> 4;                      // row = repeat(arange(MQ), 16)
    }
}

// ---------------- kNN: one wave per query ----------------
__global__ __launch_bounds__(256) void knn_kernel(const float* __restrict__ pos,
                                                  int* __restrict__ out) {
#pragma clang fp contract(off)
    const int q = blockIdx.x * 4 + (threadIdx.x >> 6);
    const int l = threadIdx.x & 63;
    if (q >= MQ) return;
    const int cidx = out[q];
    const int qb = cidx >> 12;
    const float qx = pos[(size_t)cidx * 3 + 0];
    const float qy = pos[(size_t)cidx * 3 + 1];
    const float qz = pos[(size_t)cidx * 3 + 2];
    const float* cp = pos + (size_t)qb * NPTS * 3;
    float D[64];
    float lv = __builtin_inff(); int li = 0;
#pragma unroll
    for (int j = 0; j < 64; ++j) {
        int p = j * 64 + l;
        float dx = cp[p * 3 + 0] - qx;
        float dy = cp[p * 3 + 1] - qy;
        float dz = cp[p * 3 + 2] - qz;
        float d = dx * dx + dy * dy + dz * dz;   // contract(off)
        D[j] = d;
        if (d < lv) { lv = d; li = p; }
    }
    unsigned long long mask = 0;
    int* colout = out + MQ + MQ * KK + q * KK;
    for (int r = 0; r < KK; ++r) {
        u32 klo_ = (u32)li, khi_ = __float_as_uint(lv);
        DPP_MIN(0x121); DPP_MIN(0x122); DPP_MIN(0x124); DPP_MIN(0x128);
        DPP_MIN(0x142); DPP_MIN(0x143);
        u32 bi = (u32)__builtin_amdgcn_readlane((int)klo_, 63);
        if (l == 0) colout[r] = qb * NPTS + (int)bi;
        if ((bi & 63) == (u32)l) mask |= 1ull << (bi >> 6);
        lv = __builtin_inff(); li = 0;
#pragma unroll
        for (int j = 0; j < 64; ++j) {
            bool act = ((mask >> j) & 1ull) == 0ull;
            float d = D[j];
            if (act && d < lv) { lv = d; li = j * 64 + l; }
        }
    }
}

extern "C" void kernel_launch(void* const* d_in, const int* in_sizes, int n_in,
                              void* d_out, int out_size, void* d_ws, size_t ws_size,
                              hipStream_t stream) {
    const float* pos = (const float*)d_in[0];
    int* picks = (int*)d_ws;                 // 8*1024 int32 = 32 KB
    int* out = (int*)d_out;
    fps_kernel<<<NB, 256, 0, stream>>>(pos, picks);
    build_kernel<<<(MQ * KK + 255) / 256, 256, 0, stream>>>(picks, out);
    knn_kernel<<<(MQ + 3) / 4, 256, 0, stream>>>(pos, out);
}

// Round 10
// 797.472 us; speedup vs baseline: 1.8497x; 1.8497x over previous
//
#include <hip/hip_runtime.h>

#define NPTS   4096
#define NB     8
#define M1     1024     // ceil(0.25*4096)
#define M2     820      // ceil(0.2*4096)
#define MQ     9830     // 8*1024 + 1638
#define KK     16

typedef unsigned int u32;
typedef unsigned long long u64;
typedef float f32x2 __attribute__((ext_vector_type(2)));

// 2-wide DPP lexicographic combine on (khi_,klo_) u64 key. VALU pipe.
// 0x121/0x122/0x124/0x128 = row_ror 1/2/4/8; 0x142/0x143 = row_bcast15/31.
// Lane 63 ends with the wave max. Proven bit-exact R2-R9.
#define DPP_MAX(CTRL) do {                                                         \
    u32 olo_ = (u32)__builtin_amdgcn_update_dpp((int)klo_, (int)klo_, CTRL, 0xF, 0xF, false); \
    u32 ohi_ = (u32)__builtin_amdgcn_update_dpp((int)khi_, (int)khi_, CTRL, 0xF, 0xF, false); \
    u64 ok_ = ((u64)ohi_ << 32) | olo_;                                            \
    u64 ck_ = ((u64)khi_ << 32) | klo_;                                            \
    if (ok_ > ck_) { klo_ = olo_; khi_ = ohi_; }                                   \
} while (0)

#define DPP_MIN(CTRL) do {                                                         \
    u32 olo_ = (u32)__builtin_amdgcn_update_dpp((int)klo_, (int)klo_, CTRL, 0xF, 0xF, false); \
    u32 ohi_ = (u32)__builtin_amdgcn_update_dpp((int)khi_, (int)khi_, CTRL, 0xF, 0xF, false); \
    u64 ok_ = ((u64)ohi_ << 32) | olo_;                                            \
    u64 ck_ = ((u64)khi_ << 32) | klo_;                                            \
    if (ok_ < ck_) { klo_ = olo_; khi_ = ohi_; }                                   \
} while (0)

// ---------------- FPS: 4 waves (256 thr) per cloud ----------------
// R2-exact semantics (bit-exact vs jax: d=((dx*dx+dy*dy)+dz*dz) no-contract,
// min(MD,d), argmax tie->lowest idx via u64 key dist<<32|~idx).
// R10 delta: minimize LDS ops on the per-step chain.
//   - packed sxyz[p]=float4{x,y,z,0}: candidate read = ONE ds_read_b128
//   - slots carry payload: publish b128{klo,khi,x,y}+b32{z}; read 4xb128+4xb32
//     -> no dependent sx[best] read after the select
//   - candidate read issued early, sched_barrier(0) fence (no waitcnt);
//     its lgkm wait lands in the winner branch, hidden under the DPP chain
//   - sync identical to R2: s_waitcnt lgkmcnt(0); s_barrier (asm), global
//     picks store in-loop (never waited)
__global__ __launch_bounds__(256) void fps_kernel(const float* __restrict__ pos,
                                                  int* __restrict__ picks) {
#pragma clang fp contract(off)
    __shared__ __align__(16) float4 sxyz[NPTS];            // 64 KB packed
    __shared__ __align__(16) float slotA[2][4][4];         // {klo,khi,x,y}
    __shared__ float slotZ[2][4];
    const int b = blockIdx.x;
    const int t = threadIdx.x;
    const float* cp = pos + (size_t)b * NPTS * 3;
    for (int i = t; i < NPTS * 3; i += 256) {
        float v = cp[i];
        int p = i / 3, c = i - p * 3;
        ((float*)&sxyz[p])[c] = v;
    }
    for (int i = t; i < NPTS; i += 256) ((float*)&sxyz[i])[3] = 0.0f;
    __syncthreads();

    f32x2 X[8], Y[8], Z[8], MD[8];
#pragma unroll
    for (int r = 0; r < 8; ++r) {
        int p0 = (2 * r) * 256 + t, p1 = p0 + 256;
        float4 a = sxyz[p0], c = sxyz[p1];
        X[r] = f32x2{a.x, c.x};
        Y[r] = f32x2{a.y, c.y};
        Z[r] = f32x2{a.z, c.z};
        MD[r] = f32x2{__builtin_inff(), __builtin_inff()};
    }
    if (t == 0) picks[b * M1] = 0;
    const float4 s0 = sxyz[0];
    float xl = s0.x, yl = s0.y, zl = s0.z;
    const int wave = t >> 6;

    for (int s = 1; s < M1; ++s) {
        const int par = s & 1;
        const f32x2 xl2 = f32x2{xl, xl};
        const f32x2 yl2 = f32x2{yl, yl};
        const f32x2 zl2 = f32x2{zl, zl};
        float mv[8];
        int mi[8];
#pragma unroll
        for (int r = 0; r < 8; ++r) {
            f32x2 dx = X[r] - xl2;
            f32x2 dy = Y[r] - yl2;
            f32x2 dz = Z[r] - zl2;
            f32x2 d = (dx * dx + dy * dy) + dz * dz;        // contract(off)
            f32x2 m = __builtin_elementwise_min(MD[r], d);
            MD[r] = m;
            bool c = m[1] > m[0];            // slot 2r has lower point index
            mv[r] = c ? m[1] : m[0];
            mi[r] = c ? 2 * r + 1 : 2 * r;
        }
        // tree; left always lower index -> strict > keeps lowest on ties
#pragma unroll
        for (int st = 4; st >= 1; st >>= 1) {
#pragma unroll
            for (int i = 0; i < 8; ++i) {
                if (i < st) {
                    if (mv[i + st] > mv[i]) { mv[i] = mv[i + st]; mi[i] = mi[i + st]; }
                }
            }
        }
        const int ci = (mi[0] << 8) + t;
        // own-candidate xyz: ONE b128, issued here; sched fence keeps the issue
        // above the DPP chain, the lgkm wait lands in the winner branch below
        const float4 cand = sxyz[ci];
        __builtin_amdgcn_sched_barrier(0);
        u32 klo_ = ~(u32)ci;
        u32 khi_ = __float_as_uint(mv[0]);
        const u32 mylo = klo_, myhi = khi_;
        DPP_MAX(0x121); DPP_MAX(0x122); DPP_MAX(0x124); DPP_MAX(0x128);
        DPP_MAX(0x142); DPP_MAX(0x143);
        const u32 wlo = (u32)__builtin_amdgcn_readlane((int)klo_, 63);
        if (mylo == wlo) {                   // unique winner lane per wave
            float4 pay;
            pay.x = __uint_as_float(mylo); pay.y = __uint_as_float(myhi);
            pay.z = cand.x; pay.w = cand.y;
            *(float4*)&slotA[par][wave][0] = pay;
            slotZ[par][wave] = cand.z;
        }
        asm volatile("s_waitcnt lgkmcnt(0)\n\ts_barrier" ::: "memory");
        const float4 a0 = *(const float4*)&slotA[par][0][0]; const float z0 = slotZ[par][0];
        const float4 a1 = *(const float4*)&slotA[par][1][0]; const float z1 = slotZ[par][1];
        const float4 a2 = *(const float4*)&slotA[par][2][0]; const float z2 = slotZ[par][2];
        const float4 a3 = *(const float4*)&slotA[par][3][0]; const float z3 = slotZ[par][3];
        u64 k0 = ((u64)__float_as_uint(a0.y) << 32) | __float_as_uint(a0.x);
        u64 k1 = ((u64)__float_as_uint(a1.y) << 32) | __float_as_uint(a1.x);
        u64 k2 = ((u64)__float_as_uint(a2.y) << 32) | __float_as_uint(a2.x);
        u64 k3 = ((u64)__float_as_uint(a3.y) << 32) | __float_as_uint(a3.x);
        u64 ka = k0; float xa = a0.z, ya = a0.w, za = z0;
        if (k1 > ka) { ka = k1; xa = a1.z; ya = a1.w; za = z1; }
        u64 kb = k2; float xb = a2.z, yb = a2.w, zb = z2;
        if (k3 > kb) { kb = k3; xb = a3.z; yb = a3.w; zb = z3; }
        if (kb > ka) { ka = kb; xa = xb; ya = yb; za = zb; }
        xl = xa; yl = ya; zl = za;
        if (t == 0) picks[b * M1 + s] = (int)~(u32)ka;   // global, never waited
    }
}

// ---------------- build combined_idx + row ----------------
__global__ __launch_bounds__(256) void build_kernel(const int* __restrict__ picks,
                                                    int* __restrict__ out) {
    int i = blockIdx.x * 256 + threadIdx.x;
    if (i < MQ) {
        int v;
        if (i < NB * M1) {
            int b = i >> 10;
            v = b * NPTS + picks[i];
        } else {
            int e = i - NB * M1;
            int b = e / M2;
            int j = e - b * M2;
            v = b * NPTS + picks[b * M1 + j];      // extra = prefix of base FPS
        }
        out[i] = v;
    }
    if (i < MQ * KK) {
        out[MQ + i] = i >> 4;                      // row = repeat(arange(MQ), 16)
    }
}

// ---------------- kNN: one wave per query ----------------
__global__ __launch_bounds__(256) void knn_kernel(const float* __restrict__ pos,
                                                  int* __restrict__ out) {
#pragma clang fp contract(off)
    const int q = blockIdx.x * 4 + (threadIdx.x >> 6);
    const int l = threadIdx.x & 63;
    if (q >= MQ) return;
    const int cidx = out[q];
    const int qb = cidx >> 12;
    const float qx = pos[(size_t)cidx * 3 + 0];
    const float qy = pos[(size_t)cidx * 3 + 1];
    const float qz = pos[(size_t)cidx * 3 + 2];
    const float* cp = pos + (size_t)qb * NPTS * 3;
    float D[64];
    float lv = __builtin_inff(); int li = 0;
#pragma unroll
    for (int j = 0; j < 64; ++j) {
        int p = j * 64 + l;
        float dx = cp[p * 3 + 0] - qx;
        float dy = cp[p * 3 + 1] - qy;
        float dz = cp[p * 3 + 2] - qz;
        float d = dx * dx + dy * dy + dz * dz;   // contract(off)
        D[j] = d;
        if (d < lv) { lv = d; li = p; }
    }
    unsigned long long mask = 0;
    int* colout = out + MQ + MQ * KK + q * KK;
    for (int r = 0; r < KK; ++r) {
        u32 klo_ = (u32)li, khi_ = __float_as_uint(lv);
        DPP_MIN(0x121); DPP_MIN(0x122); DPP_MIN(0x124); DPP_MIN(0x128);
        DPP_MIN(0x142); DPP_MIN(0x143);
        u32 bi = (u32)__builtin_amdgcn_readlane((int)klo_, 63);
        if (l == 0) colout[r] = qb * NPTS + (int)bi;
        if ((bi & 63) == (u32)l) mask |= 1ull << (bi >> 6);
        lv = __builtin_inff(); li = 0;
#pragma unroll
        for (int j = 0; j < 64; ++j) {
            bool act = ((mask >> j) & 1ull) == 0ull;
            float d = D[j];
            if (act && d < lv) { lv = d; li = j * 64 + l; }
        }
    }
}

extern "C" void kernel_launch(void* const* d_in, const int* in_sizes, int n_in,
                              void* d_out, int out_size, void* d_ws, size_t ws_size,
                              hipStream_t stream) {
    const float* pos = (const float*)d_in[0];
    int* picks = (int*)d_ws;                 // 8*1024 int32 = 32 KB
    int* out = (int*)d_out;
    fps_kernel<<<NB, 256, 0, stream>>>(pos, picks);
    build_kernel<<<(MQ * KK + 255) / 256, 256, 0, stream>>>(picks, out);
    knn_kernel<<<(MQ + 3) / 4, 256, 0, stream>>>(pos, out);
}